// Round 4
// baseline (296.516 us; speedup 1.0000x reference)
//
// AttentionModel: fused QKV projection + causal softmax attention, MI355X/gfx950.
// Round 7: algorithmic fusion. R4/R5/R6 proved the K-loop schedule is NOT the
// limiter (MfmaUtil pinned ~13% across 3 sync schemes; kIters=8 is too short to
// amortize fixed costs -- m102 regime). So: delete kernels & HBM round-trips.
//  - k_softmax DELETED: k_scores epilogue computes per-tile row stats
//    (m_t, sum exp(s-m_t)) via shfl row-reduce + 2-wave LDS combine -> 1MB side
//    buffers; diagonal-tile invalid entries stored as -30000 (exp -> 0).
//    k_pv merges tile-stats per row (LSE merge) in a tiny prologue, applies
//    exp(s - m_row) to A-fragments in-register (VALU co-issues with MFMA),
//    and folds 1/l into the f32 epilogue. Saves ~30us + ~134MB P traffic.
//  - k_trans DELETED: proj z==2 blocks write V directly transposed through an
//    LDS [128][136] staging tile (<=2-way banks both sides, half8 stores).
//  - K-loop = R4 form (measured best); LDS carved from one 64KB buffer so
//    epilogues can reuse it. XCD-locality grids unchanged.
// ws layout (bytes): P 0..64M | Qb 64M | Kb 80M | Sm 96M | Sl 98M | Vt 112M | Wf16 128M

#include <hip/hip_runtime.h>
#include <stdint.h>
#include <stddef.h>
#include <math.h>

typedef _Float16 half8 __attribute__((ext_vector_type(8)));
typedef float f32x4 __attribute__((ext_vector_type(4)));

#define SCALE_QK 0.04419417382415922f  // 1/sqrt(512)

__device__ __forceinline__ void gload16(const void* g, void* lds) {
  __builtin_amdgcn_global_load_lds(
      (const __attribute__((address_space(1))) void*)g,
      (__attribute__((address_space(3))) void*)lds,
      16, 0, 0);
}

// K-loop: C[128x128] = A[128xK] * B^T (B stored [N][K]), f16 MFMA, BK=64.
// LDS layout contract: element (row r, 8-group g) at halfword r*64 + (g^(r&7))*8.
// EXPA: apply exp((float)a - mr[i]) to A-fragments (row = wm*64+i*16+fr) before
// MFMA -- the fused-softmax path (A holds raw scores).
template<bool A_F32, bool EXPA>
__device__ __forceinline__ void run_kloop(const void* Arow0, const _Float16* Brow0,
                                          int lda, int ldb, int kIters,
                                          _Float16* As0, _Float16* As1,
                                          _Float16* Bs0, _Float16* Bs1,
                                          f32x4 (&acc)[4][4], const float (&mr)[4])
{
  const int tid  = threadIdx.x;
  const int lane = tid & 63;
  const int w    = tid >> 6;
  const int wm   = w >> 1, wn = w & 1;
  const int srow = tid >> 3;          // staging row within 32-row chunk
  const int sg   = tid & 7;           // staging 8-elem group slot
  const int swz  = sg ^ (srow & 7);   // swizzled group (source side)
  const int fr   = lane & 15;         // fragment m/n within 16
  const int fq   = lane >> 4;         // k-quad
  const int fx   = lane & 7;          // read-side swizzle

  f32x4 preF[8];   // A_F32 staging: 32 fp32/thread

  auto loadAreg = [&](int it) {
    const float* A = (const float*)Arow0;
    const int k0 = it * 64;
    #pragma unroll
    for (int i = 0; i < 4; ++i) {
      const float* src = A + (size_t)(i*32 + srow) * lda + (k0 + sg*8);
      preF[2*i]   = *(const f32x4*)src;
      preF[2*i+1] = *(const f32x4*)(src + 4);
    }
  };
  auto writeA = [&](_Float16* dst) {
    #pragma unroll
    for (int i = 0; i < 4; ++i) {
      f32x4 x = preF[2*i], y = preF[2*i+1];
      half8 h;
      h[0]=(_Float16)x[0]; h[1]=(_Float16)x[1]; h[2]=(_Float16)x[2]; h[3]=(_Float16)x[3];
      h[4]=(_Float16)y[0]; h[5]=(_Float16)y[1]; h[6]=(_Float16)y[2]; h[7]=(_Float16)y[3];
      *(half8*)(dst + (i*32 + srow)*64 + swz*8) = h;
    }
  };
  auto gloadA = [&](int it, _Float16* dst) {
    const _Float16* A = (const _Float16*)Arow0;
    const int k0 = it * 64;
    #pragma unroll
    for (int i = 0; i < 4; ++i)
      gload16(A + (size_t)(i*32 + srow) * lda + (k0 + swz*8), dst + i*2048 + w*512);
  };
  auto gloadB = [&](int it, _Float16* dst) {
    const int k0 = it * 64;
    #pragma unroll
    for (int i = 0; i < 4; ++i)
      gload16(Brow0 + (size_t)(i*32 + srow) * ldb + (k0 + swz*8), dst + i*2048 + w*512);
  };
  auto stage = [&](int it, _Float16* dA, _Float16* dB) {
    if constexpr (A_F32) loadAreg(it);   // A loads FIRST: writeA waits vmcnt(4)
    else                 gloadA(it, dA);
    gloadB(it, dB);
  };
  auto compute = [&](const _Float16* cAs, const _Float16* cBs) {
    #pragma unroll
    for (int ks = 0; ks < 2; ++ks) {
      half8 av[4], bv[4];
      const int slot = (ks*4 + fq) ^ fx;
      #pragma unroll
      for (int i = 0; i < 4; ++i) {
        av[i] = *(const half8*)(cAs + (wm*64 + i*16 + fr)*64 + slot*8);
        bv[i] = *(const half8*)(cBs + (wn*64 + i*16 + fr)*64 + slot*8);
      }
      if constexpr (EXPA) {
        #pragma unroll
        for (int i = 0; i < 4; ++i) {
          #pragma unroll
          for (int e = 0; e < 8; ++e)
            av[i][e] = (_Float16)__expf((float)av[i][e] - mr[i]);
        }
      }
      #pragma unroll
      for (int i = 0; i < 4; ++i) {
        #pragma unroll
        for (int j = 0; j < 4; ++j)
          acc[i][j] = __builtin_amdgcn_mfma_f32_16x16x32_f16(av[i], bv[j], acc[i][j], 0, 0, 0);
      }
    }
  };

  // prologue: tile 0 -> buf0
  stage(0, As0, Bs0);
  if constexpr (A_F32) writeA(As0);
  __syncthreads();   // drains vmcnt (gloads) + lgkm (writeA)

  // kIters even at all call sites; phases have compile-time buffer identity.
  for (int it = 0; it < kIters; it += 2) {
    // phase 0: prefetch it+1 -> buf1 while computing buf0
    stage(it + 1, As1, Bs1);
    compute(As0, Bs0);
    if constexpr (A_F32) writeA(As1);
    __syncthreads();   // vmcnt(0): it+1 staged; lgkm(0): buf0 reads done
    // phase 1: prefetch it+2 -> buf0 while computing buf1
    const bool more = (it + 2) < kIters;
    if (more) stage(it + 2, As0, Bs0);
    compute(As1, Bs1);
    if constexpr (A_F32) { if (more) writeA(As0); }
    __syncthreads();
  }
}

// ---- weights fp32 -> f16 (3 x 512x512 concatenated) ----
__global__ __launch_bounds__(256) void k_cvtw(const float* __restrict__ Wq,
                                              const float* __restrict__ Wk,
                                              const float* __restrict__ Wv,
                                              _Float16* __restrict__ Wb)
{
  const int t = blockIdx.x * 256 + threadIdx.x;
  const int base = t * 8;                 // 786432 total elems
  const int z = base >> 18;               // 262144 per matrix
  const int off = base & 262143;
  const float* src = (z == 0) ? Wq : ((z == 1) ? Wk : Wv);
  f32x4 a = *(const f32x4*)(src + off);
  f32x4 b = *(const f32x4*)(src + off + 4);
  half8 h;
  h[0]=(_Float16)a[0]; h[1]=(_Float16)a[1]; h[2]=(_Float16)a[2]; h[3]=(_Float16)a[3];
  h[4]=(_Float16)b[0]; h[5]=(_Float16)b[1]; h[6]=(_Float16)b[2]; h[7]=(_Float16)b[3];
  *(half8*)(Wb + base) = h;
}

// ---- projections: X[16384x512](fp32) @ W^T + bias -> f16 ----
// 1D grid 1536: xcd = bid%8; i = bid/8; panel p = xcd*48 + i/4; nt = i%4;
// z = p/128, mt = p%128. z==2 (V) writes DIRECTLY TRANSPOSED to Vt via LDS.
__global__ __launch_bounds__(256) void k_proj(const float* __restrict__ q,
                                              const float* __restrict__ k,
                                              const float* __restrict__ v,
                                              const _Float16* __restrict__ Wb,
                                              const float* __restrict__ bq,
                                              const float* __restrict__ bk,
                                              const float* __restrict__ bv,
                                              _Float16* __restrict__ Qb,
                                              _Float16* __restrict__ Kb,
                                              _Float16* __restrict__ Vt)
{
  __shared__ __align__(16) _Float16 LDSbuf[4*128*64];   // 64 KB, carved
  _Float16* As0 = LDSbuf;
  _Float16* As1 = LDSbuf + 8192;
  _Float16* Bs0 = LDSbuf + 16384;
  _Float16* Bs1 = LDSbuf + 24576;

  const int bid = blockIdx.x;
  const int xcd = bid & 7, i = bid >> 3;
  const int p = xcd * 48 + (i >> 2);
  const int nt = i & 3;
  const int z = p >> 7, mt = p & 127;

  const float* A     = (z == 0) ? q  : (z == 1) ? k  : v;
  const float* bia   = (z == 0) ? bq : (z == 1) ? bk : bv;
  const _Float16* B  = Wb + (size_t)z * 512 * 512;

  f32x4 acc[4][4] = {};
  const float mrd[4] = {0,0,0,0};
  run_kloop<true, false>(A + (size_t)mt*128*512, B + (size_t)nt*128*512, 512, 512, 8,
                         As0, As1, Bs0, Bs1, acc, mrd);

  const int tid = threadIdx.x;
  const int lane = tid & 63, w = tid >> 6;
  const int wm = w >> 1, wn = w & 1;
  const int fr = lane & 15, fq = lane >> 4;   // C/D: col=lane&15, row=(lane>>4)*4+reg

  if (z < 2) {
    _Float16* C = (z == 0) ? Qb : Kb;
    #pragma unroll
    for (int j = 0; j < 4; ++j) {
      const int col = nt*128 + wn*64 + j*16 + fr;
      const float bval = bia[col];
      #pragma unroll
      for (int i2 = 0; i2 < 4; ++i2) {
        const int row = mt*128 + wm*64 + i2*16 + fq*4;
        #pragma unroll
        for (int r = 0; r < 4; ++r)
          C[(size_t)(row + r) * 512 + col] = (_Float16)(acc[i2][j][r] + bval);
      }
    }
  } else {
    // V: stage transposed tile in LDS [col 128][row 128+pad8], then write Vt coalesced.
    _Float16* sm = LDSbuf;   // 128*136 halfs = 34 KB (kloop done; LDS free)
    #pragma unroll
    for (int j = 0; j < 4; ++j) {
      const int colloc = wn*64 + j*16 + fr;
      const float bval = bia[nt*128 + colloc];
      #pragma unroll
      for (int i2 = 0; i2 < 4; ++i2) {
        const int rowloc = wm*64 + i2*16 + fq*4;
        #pragma unroll
        for (int r = 0; r < 4; ++r)
          sm[colloc*136 + rowloc + r] = (_Float16)(acc[i2][j][r] + bval);
      }
    }
    __syncthreads();
    const int bb = mt >> 4, s0 = (mt & 15) * 128;
    #pragma unroll
    for (int q8 = 0; q8 < 8; ++q8) {
      const int dloc = q8*16 + (tid >> 4);
      const int ch   = tid & 15;
      half8 o = *(const half8*)&sm[dloc*136 + ch*8];
      *(half8*)(Vt + ((size_t)bb*512 + nt*128 + dloc)*2048 + s0 + ch*8) = o;
    }
  }
}

// ---- scores: S = Q K^T * scale, raw (unsoftmaxed) + per-tile row stats ----
// 1D grid 1088: b = bid%8 (-> XCD b); t = bid/8 triangular-decoded to (qt,kt).
// Diagonal tile: invalid (col>row) entries stored as -30000 (exp -> 0).
// Stats: Sm[(b,qt,kt)*128+row] = tile row max; Sl = sum exp(s - Sm).
__global__ __launch_bounds__(256) void k_scores(const _Float16* __restrict__ Qb,
                                                const _Float16* __restrict__ Kb,
                                                _Float16* __restrict__ P,
                                                float* __restrict__ Sm,
                                                float* __restrict__ Sl)
{
  __shared__ __align__(16) _Float16 LDSbuf[4*128*64];
  _Float16* As0 = LDSbuf;
  _Float16* As1 = LDSbuf + 8192;
  _Float16* Bs0 = LDSbuf + 16384;
  _Float16* Bs1 = LDSbuf + 24576;

  const int bid = blockIdx.x;
  const int b = bid & 7;
  const int t = bid >> 3;
  int qt = (int)((sqrtf(8.0f * (float)t + 1.0f) - 1.0f) * 0.5f);
  int base = (qt * (qt + 1)) >> 1;
  if (t < base)                { --qt; base = (qt * (qt + 1)) >> 1; }
  else if (t >= base + qt + 1) { ++qt; base = (qt * (qt + 1)) >> 1; }
  const int kt = t - base;
  const bool diag = (kt == qt);

  f32x4 acc[4][4] = {};
  const float mrd[4] = {0,0,0,0};
  run_kloop<false, false>(Qb + ((size_t)b*2048 + qt*128)*512,
                          Kb + ((size_t)b*2048 + kt*128)*512,
                          512, 512, 8, As0, As1, Bs0, Bs1, acc, mrd);

  const int tid = threadIdx.x;
  const int lane = tid & 63, w = tid >> 6;
  const int wm = w >> 1, wn = w & 1;
  const int fr = lane & 15, fq = lane >> 4;

  // ---- per-tile row stats (m_t, l_t) ----
  float* sf = (float*)LDSbuf;   // 512 floats scratch (kloop done)
  float rmax[4][4];
  #pragma unroll
  for (int i = 0; i < 4; ++i) {
    #pragma unroll
    for (int r = 0; r < 4; ++r) {
      const int rl = wm*64 + i*16 + fq*4 + r;
      float v = -1e30f;
      #pragma unroll
      for (int j = 0; j < 4; ++j) {
        const int cl = wn*64 + j*16 + fr;
        const float sc = acc[i][j][r] * SCALE_QK;
        v = fmaxf(v, (diag && cl > rl) ? -1e30f : sc);
      }
      #pragma unroll
      for (int d = 1; d < 16; d <<= 1) v = fmaxf(v, __shfl_xor(v, d, 64));
      rmax[i][r] = v;
      if (fr == 0) sf[wn*128 + rl] = v;
    }
  }
  __syncthreads();
  float M[4][4];
  #pragma unroll
  for (int i = 0; i < 4; ++i)
    #pragma unroll
    for (int r = 0; r < 4; ++r) {
      const int rl = wm*64 + i*16 + fq*4 + r;
      M[i][r] = fmaxf(sf[rl], sf[128 + rl]);
    }
  #pragma unroll
  for (int i = 0; i < 4; ++i) {
    #pragma unroll
    for (int r = 0; r < 4; ++r) {
      const int rl = wm*64 + i*16 + fq*4 + r;
      float sacc = 0.f;
      #pragma unroll
      for (int j = 0; j < 4; ++j) {
        const int cl = wn*64 + j*16 + fr;
        const float sc = acc[i][j][r] * SCALE_QK;
        const float se = (diag && cl > rl) ? -1e30f : sc;
        sacc += __expf(se - M[i][r]);
      }
      #pragma unroll
      for (int d = 1; d < 16; d <<= 1) sacc += __shfl_xor(sacc, d, 64);
      if (fr == 0) sf[256 + wn*128 + rl] = sacc;
    }
  }
  __syncthreads();
  if (wn == 0 && fr == 0) {
    const size_t sbase = (size_t)((b*16 + qt)*16 + kt) * 128;
    #pragma unroll
    for (int i = 0; i < 4; ++i)
      #pragma unroll
      for (int r = 0; r < 4; ++r) {
        const int rl = wm*64 + i*16 + fq*4 + r;
        Sm[sbase + rl] = M[i][r];
        Sl[sbase + rl] = sf[256 + rl] + sf[384 + rl];
      }
  }

  // ---- store raw S (masked on diagonal) ----
  #pragma unroll
  for (int i = 0; i < 4; ++i) {
    const int rl = wm*64 + i*16 + fq*4;
    #pragma unroll
    for (int j = 0; j < 4; ++j) {
      const int cl = wn*64 + j*16 + fr;
      #pragma unroll
      for (int r = 0; r < 4; ++r) {
        const float sc = acc[i][j][r] * SCALE_QK;
        const bool msk = diag && (cl > rl + r);
        P[((size_t)b*2048 + qt*128 + rl + r) * 2048 + kt*128 + cl] =
            msk ? (_Float16)(-30000.0f) : (_Float16)sc;
      }
    }
  }
}

// ---- out = softmax(S) @ V, fused: stats merge + in-fragment exp + 1/l scale ----
// 1D grid 512: b = bid%8 (-> XCD b); r = bid/8: qi=r/4 interleaved long/short,
// dt=r%4. A-operand = raw S tiles (P); B = Vt[d][s]; causal K-extent.
__global__ __launch_bounds__(256) void k_pv(const _Float16* __restrict__ P,
                                            const float* __restrict__ Sm,
                                            const float* __restrict__ Sl,
                                            const _Float16* __restrict__ Vt,
                                            float* __restrict__ Out)
{
  __shared__ __align__(16) _Float16 LDSbuf[4*128*64];
  _Float16* As0 = LDSbuf;
  _Float16* As1 = LDSbuf + 8192;
  _Float16* Bs0 = LDSbuf + 16384;
  _Float16* Bs1 = LDSbuf + 24576;

  const int bid = blockIdx.x;
  const int b = bid & 7;
  const int r0 = bid >> 3;
  const int qi = r0 >> 2, dt = r0 & 3;
  const int qt = (qi & 1) ? (15 - (qi >> 1)) : (qi >> 1);

  const int tid = threadIdx.x;
  const int lane = tid & 63, w = tid >> 6;
  const int wm = w >> 1, wn = w & 1;
  const int fr = lane & 15, fq = lane >> 4;

  // ---- merge per-tile stats into per-row (m, 1/l) via LDS scratch ----
  float* tmp = (float*)LDSbuf;   // 256 floats, consumed before kloop staging
  const size_t sbase = (size_t)((b*16 + qt)*16) * 128;
  if (tid < 128) {
    float m = -1e30f;
    for (int kt = 0; kt <= qt; ++kt) m = fmaxf(m, Sm[sbase + kt*128 + tid]);
    float l = 0.f;
    for (int kt = 0; kt <= qt; ++kt)
      l += Sl[sbase + kt*128 + tid] * __expf(Sm[sbase + kt*128 + tid] - m);
    tmp[tid] = m;
    tmp[128 + tid] = 1.0f / l;
  }
  __syncthreads();
  float mr[4];
  f32x4 il[4];
  #pragma unroll
  for (int i = 0; i < 4; ++i) mr[i] = tmp[wm*64 + i*16 + fr];
  #pragma unroll
  for (int i = 0; i < 4; ++i) il[i] = *(const f32x4*)&tmp[128 + wm*64 + i*16 + fq*4];
  __syncthreads();   // done with tmp; kloop may overwrite LDS

  f32x4 acc[4][4] = {};
  run_kloop<false, true>(P  + ((size_t)b*2048 + qt*128)*2048,
                         Vt + ((size_t)b*512  + dt*128)*2048,
                         2048, 2048, (qt + 1) * 2, As0, As1, Bs0, Bs1, acc, mr);

  #pragma unroll
  for (int i = 0; i < 4; ++i) {
    const int row = qt*128 + wm*64 + i*16 + fq*4;
    #pragma unroll
    for (int j = 0; j < 4; ++j) {
      const int col = dt*128 + wn*64 + j*16 + fr;
      #pragma unroll
      for (int r = 0; r < 4; ++r)
        Out[((size_t)b*2048 + row + r) * 512 + col] = acc[i][j][r] * il[i][r];
    }
  }
}

extern "C" void kernel_launch(void* const* d_in, const int* in_sizes, int n_in,
                              void* d_out, int out_size, void* d_ws, size_t ws_size,
                              hipStream_t stream) {
  (void)in_sizes; (void)n_in; (void)out_size;
  const float* q  = (const float*)d_in[0];
  const float* k  = (const float*)d_in[1];
  const float* v  = (const float*)d_in[2];
  // d_in[3] = causal mask: always tril per setup; implemented structurally.
  const float* Wq = (const float*)d_in[4];
  const float* bq = (const float*)d_in[5];
  const float* Wk = (const float*)d_in[6];
  const float* bk = (const float*)d_in[7];
  const float* Wv = (const float*)d_in[8];
  const float* bv = (const float*)d_in[9];

  const size_t OFF_P  = 0;
  const size_t OFF_Q  = (size_t)64 << 20;
  const size_t OFF_K  = (size_t)80 << 20;
  const size_t OFF_SM = (size_t)96 << 20;   // 1 MB (8*16*16*128 f32)
  const size_t OFF_SL = (size_t)98 << 20;   // 1 MB
  const size_t OFF_VT = (size_t)112 << 20;
  const size_t OFF_W  = (size_t)128 << 20;
  const size_t NEEDED = OFF_W + (size_t)3 * 512 * 512 * sizeof(_Float16);
  if (ws_size < NEEDED) return;  // diagnostic: poison-level absmax => ws too small

  char* ws = (char*)d_ws;
  _Float16* P  = (_Float16*)(ws + OFF_P);
  _Float16* Qb = (_Float16*)(ws + OFF_Q);
  _Float16* Kb = (_Float16*)(ws + OFF_K);
  float*    Sm = (float*)(ws + OFF_SM);
  float*    Sl = (float*)(ws + OFF_SL);
  _Float16* Vt = (_Float16*)(ws + OFF_VT);
  _Float16* Wb = (_Float16*)(ws + OFF_W);
  float* Out = (float*)d_out;

  k_cvtw   <<<dim3(384),  dim3(256), 0, stream>>>(Wq, Wk, Wv, Wb);
  k_proj   <<<dim3(1536), dim3(256), 0, stream>>>(q, k, v, Wb, bq, bk, bv, Qb, Kb, Vt);
  k_scores <<<dim3(1088), dim3(256), 0, stream>>>(Qb, Kb, P, Sm, Sl);
  k_pv     <<<dim3(512),  dim3(256), 0, stream>>>(P, Sm, Sl, Vt, Out);
}